// Round 11
// baseline (898.544 us; speedup 1.0000x reference)
//
#include <hip/hip_runtime.h>
#include <hip/hip_bf16.h>
#include <math.h>

#define B_ 16
#define N_ 512
#define D_ 256
#define HEADS_ 8
#define DH_ 32
#define HIDEF_ 1024
#define NBLK_ 16
#define BS_ 32
#define LEVELS_ 5
#define PYOUT_ 128
#define ROWS_ (B_ * N_)   // 8192
#define FCL_K 327680
#define FCL_KB 256
#define FCL_CHUNKS 1280

typedef __attribute__((ext_vector_type(8))) short short8;
typedef __attribute__((ext_vector_type(4))) short short4v;
typedef __attribute__((ext_vector_type(4))) unsigned short ushort4v;
typedef __attribute__((ext_vector_type(4))) float f32x4;

__device__ __forceinline__ float bf2f(short u) {
    return __uint_as_float(((unsigned int)(unsigned short)u) << 16);
}
__device__ __forceinline__ unsigned short f2bf(float x) {
    __hip_bfloat16 h = __float2bfloat16(x);
    return *reinterpret_cast<unsigned short*>(&h);
}

__device__ __forceinline__ float gelu_f(float x) {
    float x3 = x * x * x;
    return 0.5f * x * (1.f + tanhf(0.7978845608028654f * (x + 0.044715f * x3)));
}

// ---------------------------------------------------------------- combined prep
__global__ __launch_bounds__(256) void prep_kernel(
    const float* __restrict__ patch_W, const float* __restrict__ Wqkv,
    const float* __restrict__ Wo, const float* __restrict__ ff_W1,
    const float* __restrict__ ff_W2, const float* __restrict__ pyr_W,
    const float* __restrict__ x_in,
    __hip_bfloat16* __restrict__ patchWt, __hip_bfloat16* __restrict__ qkvWt,
    __hip_bfloat16* __restrict__ WoWt, __hip_bfloat16* __restrict__ W1t,
    __hip_bfloat16* __restrict__ W2t, __hip_bfloat16* __restrict__ pyrWt,
    float* __restrict__ pos, __hip_bfloat16* __restrict__ Xb) {
    __shared__ float tt[32][33];
    int bid = blockIdx.x, t = threadIdx.x;
    if (bid >= 1504) {           // x -> bf16, 2048 elems/block
        int base = (bid - 1504) * 2048 + t * 8;
        float4 a = *(const float4*)&x_in[base];
        float4 b = *(const float4*)&x_in[base + 4];
        ushort4v u0 = {f2bf(a.x), f2bf(a.y), f2bf(a.z), f2bf(a.w)};
        ushort4v u1 = {f2bf(b.x), f2bf(b.y), f2bf(b.z), f2bf(b.w)};
        *(ushort4v*)((short*)Xb + base) = u0;
        *(ushort4v*)((short*)Xb + base + 4) = u1;
        return;
    }
    if (bid >= 992) {            // pos table
        int idx = (bid - 992) * 256 + t;
        int n = idx >> 8, i = idx & 255;
        double angle = (double)n / pow(10000.0, (double)(2 * (i >> 1)) / 256.0);
        pos[idx] = (float)((i & 1) ? cos(angle) : sin(angle));
        return;
    }
    const float* W; __hip_bfloat16* Wt; int K, N, bx, by;
    if (bid < 64)       { W = patch_W; Wt = patchWt; K = 256; N = 256; bx = bid % 8; by = bid / 8; }
    else if (bid < 256) { int l = bid - 64;  W = Wqkv;  Wt = qkvWt; K = 256; N = 768;  bx = l % 24; by = l / 24; }
    else if (bid < 320) { int l = bid - 256; W = Wo;    Wt = WoWt;  K = 256; N = 256;  bx = l % 8;  by = l / 8; }
    else if (bid < 576) { int l = bid - 320; W = ff_W1; Wt = W1t;   K = 256; N = 1024; bx = l % 32; by = l / 32; }
    else if (bid < 832) { int l = bid - 576; W = ff_W2; Wt = W2t;   K = 1024; N = 256; bx = l % 8;  by = l / 8; }
    else                { int l = bid - 832; int z = l / 32; int r = l % 32;
                          W = pyr_W + (size_t)z * 256 * 128; Wt = pyrWt + (size_t)z * 256 * 128;
                          K = 256; N = 128; bx = r % 4; by = r / 4; }
    int bx32 = bx * 32, by32 = by * 32;
    int tx = t & 31, ty = t >> 5;
#pragma unroll
    for (int i = 0; i < 32; i += 8)
        tt[ty + i][tx] = W[(size_t)(by32 + ty + i) * N + bx32 + tx];
    __syncthreads();
#pragma unroll
    for (int i = 0; i < 32; i += 8)
        Wt[(size_t)(bx32 + ty + i) * K + by32 + tx] = __float2bfloat16(tt[tx][ty + i]);
}

// ---------------------------------------------------------------- bf16 MFMA GEMM
// BK=64, double-buffered, XCD-aware bijective block swizzle (grids % 8 == 0).
template <int ACT, bool OUTF, bool OUTB, bool STATS, int BM, int BN>
__global__ __launch_bounds__(256) void bgemm_kernel(
    const __hip_bfloat16* __restrict__ A, const __hip_bfloat16* __restrict__ Wt,
    const float* __restrict__ bias, const float* __restrict__ resid,
    float* __restrict__ C, __hip_bfloat16* __restrict__ Cb, int M, int Nn, int K,
    float* __restrict__ bnp) {
    __shared__ __hip_bfloat16 Alds[2][BM * 64];
    __shared__ __hip_bfloat16 Blds[2][BN * 64];
    constexpr int WM_ = (BM == 128 && BN == 64) ? 4 : 2;
    constexpr int WN_ = 4 / WM_;
    constexpr int WH = BM / WM_;
    constexpr int WC = BN / WN_;
    constexpr int MW = WH / 16;
    constexpr int NW = WC / 16;
    constexpr int AR = BM / 32;
    constexpr int BR = BN / 32;
    int tid = threadIdx.x;
    int wid = tid >> 6, lane = tid & 63;
    int flat = blockIdx.y * gridDim.x + blockIdx.x;
    int q8 = (gridDim.x * gridDim.y) >> 3;
    int wg = (flat & 7) * q8 + (flat >> 3);
    int bx = wg % gridDim.x, by = wg / gridDim.x;
    int row0 = by * BM, col0 = bx * BN;
    int wr = wid / WN_, wc = wid % WN_;
    int r16 = lane & 15, kq = lane >> 4;

    f32x4 acc[MW][NW];
#pragma unroll
    for (int m = 0; m < MW; m++)
#pragma unroll
        for (int n = 0; n < NW; n++) acc[m][n] = (f32x4){0.f, 0.f, 0.f, 0.f};

    auto stage = [&](int b, int k0) {
#pragma unroll
        for (int i = 0; i < AR; i++) {
            int slot = i * 256 + tid;
            int row = slot >> 3, qp = slot & 7;
            int q = qp ^ ((row >> 1) & 7);
            const __hip_bfloat16* ga = A + (size_t)(row0 + row) * K + k0 + q * 8;
            __builtin_amdgcn_global_load_lds(
                (const __attribute__((address_space(1))) void*)ga,
                (__attribute__((address_space(3))) void*)((char*)&Alds[b][0] + i * 4096 + wid * 1024),
                16, 0, 0);
        }
#pragma unroll
        for (int i = 0; i < BR; i++) {
            int slot = i * 256 + tid;
            int row = slot >> 3, qp = slot & 7;
            int q = qp ^ ((row >> 1) & 7);
            const __hip_bfloat16* gb = Wt + (size_t)(col0 + row) * K + k0 + q * 8;
            __builtin_amdgcn_global_load_lds(
                (const __attribute__((address_space(1))) void*)gb,
                (__attribute__((address_space(3))) void*)((char*)&Blds[b][0] + i * 4096 + wid * 1024),
                16, 0, 0);
        }
    };

    stage(0, 0);
    __syncthreads();
    int cur = 0;
    for (int k0 = 0; k0 < K; k0 += 64) {
        if (k0 + 64 < K) stage(cur ^ 1, k0 + 64);
#pragma unroll
        for (int h = 0; h < 2; h++) {
            short8 af[MW], bf4[NW];
#pragma unroll
            for (int m = 0; m < MW; m++) {
                int row = wr * WH + m * 16 + r16;
                int phys = (h * 4 + kq) ^ ((row >> 1) & 7);
                af[m] = *reinterpret_cast<const short8*>(
                    reinterpret_cast<const char*>(&Alds[cur][0]) + row * 128 + phys * 16);
            }
#pragma unroll
            for (int n = 0; n < NW; n++) {
                int row = wc * WC + n * 16 + r16;
                int phys = (h * 4 + kq) ^ ((row >> 1) & 7);
                bf4[n] = *reinterpret_cast<const short8*>(
                    reinterpret_cast<const char*>(&Blds[cur][0]) + row * 128 + phys * 16);
            }
#pragma unroll
            for (int m = 0; m < MW; m++)
#pragma unroll
                for (int n = 0; n < NW; n++)
                    acc[m][n] = __builtin_amdgcn_mfma_f32_16x16x32_bf16(af[m], bf4[n], acc[m][n], 0, 0, 0);
        }
        __syncthreads();
        cur ^= 1;
    }

    int rg = lane >> 4;
    float s1a[NW], s2a[NW];
#pragma unroll
    for (int n = 0; n < NW; n++) { s1a[n] = 0.f; s2a[n] = 0.f; }
#pragma unroll
    for (int n = 0; n < NW; n++) {
        int cc = col0 + wc * WC + n * 16 + r16;
        float bv = bias[cc];
#pragma unroll
        for (int m = 0; m < MW; m++) {
            int rb = row0 + wr * WH + m * 16 + rg * 4;
#pragma unroll
            for (int j = 0; j < 4; j++) {
                int r = rb + j;
                float v = acc[m][n][j] + bv;
                if (resid) v += resid[(size_t)r * Nn + cc];
                if (ACT == 1) v = gelu_f(v);
                if (OUTF) C[(size_t)r * Nn + cc] = v;
                if (OUTB) Cb[(size_t)r * Nn + cc] = __float2bfloat16(v);
                if (STATS) { s1a[n] += v; s2a[n] += v * v; }
            }
        }
    }
    if (STATS) {
        float* sc = (float*)&Alds[0][0];
        int part = wid * 4 + rg;
#pragma unroll
        for (int n = 0; n < NW; n++) {
            int c = wc * WC + n * 16 + r16;
            sc[c * 16 + part] = s1a[n];
            sc[BN * 16 + c * 16 + part] = s2a[n];
        }
        __syncthreads();
        if (tid < BN) {
            float a = 0.f, b2 = 0.f;
#pragma unroll
            for (int p = 0; p < 16; p++) {
                a += sc[tid * 16 + p];
                b2 += sc[BN * 16 + tid * 16 + p];
            }
            bnp[by * 256 + col0 + tid] = a;
            bnp[32768 + by * 256 + col0 + tid] = b2;
        }
    }
}

// ---------------------------------------------------------------- fused BN1 + FF1
// Grid (8,128). BM=64, BN=128, 4 waves 1x4 (wave = 32-col group, full 64 rows).
// Phase 1: BNP stats finish. Phase 2: BN-apply T rows -> swizzled bf16 A-LDS
// (+ H fp32 write from bx==0 block). Phase 3: MIDb = gelu(A @ W1^T + b1).
__global__ __launch_bounds__(256) void bnff1_kernel(
    const float* __restrict__ T, const float* __restrict__ bnp,
    const float* __restrict__ bng, const float* __restrict__ bnb,
    const __hip_bfloat16* __restrict__ W1t, const float* __restrict__ ff_b1,
    float* __restrict__ H, __hip_bfloat16* __restrict__ MIDb) {
    __shared__ char __attribute__((aligned(16))) smem[67584];
    // A [0,32768): 64 rows x 512B, swz phys = c ^ (r&7)
    // B [32768,65536): 2 x 16KB dbuf
    // sm/sv [65536,67584)
    float* sm = (float*)(smem + 65536);
    float* sv = sm + 256;
    int tid = threadIdx.x;
    int wid = tid >> 6, lane = tid & 63;
    int flat = blockIdx.y * gridDim.x + blockIdx.x;   // (8,128)
    int q8 = (gridDim.x * gridDim.y) >> 3;
    int wg = (flat & 7) * q8 + (flat >> 3);
    int bx = wg & 7, by = wg >> 3;
    int row0 = by * 64, col0 = bx * 128;
    int r16 = lane & 15, kq = lane >> 4, rg = lane >> 4;

    // phase 1: stats
    {
        float s = 0.f, s2 = 0.f;
#pragma unroll 4
        for (int yy = 0; yy < 128; yy++) {
            s += bnp[yy * 256 + tid];
            s2 += bnp[32768 + yy * 256 + tid];
        }
        float m = s * (1.f / 8192.f);
        sm[tid] = m;
        sv[tid] = rsqrtf(s2 * (1.f / 8192.f) - m * m + 1e-5f);
    }
    __syncthreads();
    // phase 2: BN apply -> A LDS (+ H when bx==0)
    {
        float4 m4 = ((const float4*)sm)[lane];
        float4 r4 = ((const float4*)sv)[lane];
        float4 g4 = ((const float4*)bng)[lane];
        float4 b4 = ((const float4*)bnb)[lane];
#pragma unroll
        for (int rr = 0; rr < 16; rr++) {
            int r = wid * 16 + rr;
            int grow = row0 + r;
            float4 x4 = ((const float4*)(T + (size_t)grow * D_))[lane];
            float o0 = (x4.x - m4.x) * r4.x * g4.x + b4.x;
            float o1 = (x4.y - m4.y) * r4.y * g4.y + b4.y;
            float o2 = (x4.z - m4.z) * r4.z * g4.z + b4.z;
            float o3 = (x4.w - m4.w) * r4.w * g4.w + b4.w;
            ushort4v u = {f2bf(o0), f2bf(o1), f2bf(o2), f2bf(o3)};
            int c = lane >> 1;
            int phys = c ^ (r & 7);
            *(ushort4v*)(smem + r * 512 + phys * 16 + (lane & 1) * 8) = u;
            if (bx == 0)
                ((float4*)(H + (size_t)grow * D_))[lane] = (float4){o0, o1, o2, o3};
        }
    }
    // phase 3: GEMM, B dbuf
    auto stageB = [&](int b, int k0) {
#pragma unroll
        for (int i = 0; i < 4; i++) {
            int slot = i * 256 + tid;
            int row = slot >> 3, qp = slot & 7;
            int q = qp ^ ((row >> 1) & 7);
            const __hip_bfloat16* gb = W1t + (size_t)(col0 + row) * 256 + k0 + q * 8;
            __builtin_amdgcn_global_load_lds(
                (const __attribute__((address_space(1))) void*)gb,
                (__attribute__((address_space(3))) void*)(smem + 32768 + b * 16384 + i * 4096 + wid * 1024),
                16, 0, 0);
        }
    };
    f32x4 acc[4][2];
#pragma unroll
    for (int m = 0; m < 4; m++)
#pragma unroll
        for (int n = 0; n < 2; n++) acc[m][n] = (f32x4){0.f, 0.f, 0.f, 0.f};
    stageB(0, 0);
    __syncthreads();   // A ds_writes + B buf0 ready
    int cur = 0;
    for (int k0 = 0; k0 < 256; k0 += 64) {
        if (k0 + 64 < 256) stageB(cur ^ 1, k0 + 64);
        const char* Bb = smem + 32768 + cur * 16384;
#pragma unroll
        for (int h = 0; h < 2; h++) {
            int ac = (k0 >> 3) + h * 4 + kq;
            short8 af[4];
#pragma unroll
            for (int m = 0; m < 4; m++) {
                int arow = m * 16 + r16;
                int aphys = ac ^ (arow & 7);
                af[m] = *(const short8*)(smem + arow * 512 + aphys * 16);
            }
            short8 bf4[2];
#pragma unroll
            for (int n = 0; n < 2; n++) {
                int brow = wid * 32 + n * 16 + r16;
                int bphys = (h * 4 + kq) ^ ((brow >> 1) & 7);
                bf4[n] = *(const short8*)(Bb + brow * 128 + bphys * 16);
            }
#pragma unroll
            for (int m = 0; m < 4; m++)
#pragma unroll
                for (int n = 0; n < 2; n++)
                    acc[m][n] = __builtin_amdgcn_mfma_f32_16x16x32_bf16(af[m], bf4[n], acc[m][n], 0, 0, 0);
        }
        __syncthreads();
        cur ^= 1;
    }
#pragma unroll
    for (int n = 0; n < 2; n++) {
        int cc = col0 + wid * 32 + n * 16 + r16;
        float bv = ff_b1[cc];
#pragma unroll
        for (int m = 0; m < 4; m++) {
            int rb = row0 + m * 16 + rg * 4;
#pragma unroll
            for (int j = 0; j < 4; j++) {
                float v = gelu_f(acc[m][n][j] + bv);
                MIDb[(size_t)(rb + j) * HIDEF_ + cc] = __float2bfloat16(v);
            }
        }
    }
}

// ---------------------------------------------------------------- patchln (it=0 only)
__global__ __launch_bounds__(256) void patchln_kernel(
    const __hip_bfloat16* __restrict__ A, const __hip_bfloat16* __restrict__ Wt,
    const float* __restrict__ bias, const float* __restrict__ lng,
    const float* __restrict__ lnb, const float* __restrict__ pos,
    float* __restrict__ H, __hip_bfloat16* __restrict__ Hb) {
    __shared__ char __attribute__((aligned(16))) smem[73728];
    float (*Cls)[260] = (float(*)[260])smem;
    int tid = threadIdx.x;
    int wid = tid >> 6, lane = tid & 63;
    int row0 = blockIdx.x * 32;
    int r16 = lane & 15, kq = lane >> 4, g = lane >> 4;

    f32x4 acc[2][4];
#pragma unroll
    for (int m = 0; m < 2; m++)
#pragma unroll
        for (int n = 0; n < 4; n++) acc[m][n] = (f32x4){0.f, 0.f, 0.f, 0.f};

    auto stage = [&](int b, int k0) {
        {
            int row = tid >> 3, qp = tid & 7;
            int q = qp ^ ((row >> 1) & 7);
            const __hip_bfloat16* ga = A + (size_t)(row0 + row) * 256 + k0 + q * 8;
            __builtin_amdgcn_global_load_lds(
                (const __attribute__((address_space(1))) void*)ga,
                (__attribute__((address_space(3))) void*)(smem + b * 4096 + wid * 1024),
                16, 0, 0);
        }
#pragma unroll
        for (int i = 0; i < 8; i++) {
            int slot = i * 256 + tid;
            int row = slot >> 3, qp = slot & 7;
            int q = qp ^ ((row >> 1) & 7);
            const __hip_bfloat16* gb = Wt + (size_t)row * 256 + k0 + q * 8;
            __builtin_amdgcn_global_load_lds(
                (const __attribute__((address_space(1))) void*)gb,
                (__attribute__((address_space(3))) void*)(smem + 8192 + b * 32768 + i * 4096 + wid * 1024),
                16, 0, 0);
        }
    };

    stage(0, 0);
    __syncthreads();
    int cur = 0;
    for (int k0 = 0; k0 < 256; k0 += 64) {
        if (k0 + 64 < 256) stage(cur ^ 1, k0 + 64);
        const char* Ab = smem + cur * 4096;
        const char* Bb = smem + 8192 + cur * 32768;
#pragma unroll
        for (int h = 0; h < 2; h++) {
            short8 af[2], bf4[4];
#pragma unroll
            for (int m = 0; m < 2; m++) {
                int row = m * 16 + r16;
                int phys = (h * 4 + kq) ^ ((row >> 1) & 7);
                af[m] = *reinterpret_cast<const short8*>(Ab + row * 128 + phys * 16);
            }
#pragma unroll
            for (int n = 0; n < 4; n++) {
                int row = wid * 64 + n * 16 + r16;
                int phys = (h * 4 + kq) ^ ((row >> 1) & 7);
                bf4[n] = *reinterpret_cast<const short8*>(Bb + row * 128 + phys * 16);
            }
#pragma unroll
            for (int m = 0; m < 2; m++)
#pragma unroll
                for (int n = 0; n < 4; n++)
                    acc[m][n] = __builtin_amdgcn_mfma_f32_16x16x32_bf16(af[m], bf4[n], acc[m][n], 0, 0, 0);
        }
        __syncthreads();
        cur ^= 1;
    }
#pragma unroll
    for (int n = 0; n < 4; n++) {
        int col = wid * 64 + n * 16 + r16;
        float bv = bias[col];
#pragma unroll
        for (int m = 0; m < 2; m++)
#pragma unroll
            for (int j = 0; j < 4; j++)
                Cls[m * 16 + g * 4 + j][col] = acc[m][n][j] + bv;
    }
    __syncthreads();
    float4 g4 = ((const float4*)lng)[lane];
    float4 b4 = ((const float4*)lnb)[lane];
#pragma unroll
    for (int rr = 0; rr < 8; rr++) {
        int r = wid * 8 + rr;
        float4 v = *(const float4*)&Cls[r][lane * 4];
        float s = v.x + v.y + v.z + v.w;
#pragma unroll
        for (int mk = 32; mk; mk >>= 1) s += __shfl_xor(s, mk);
        float mean = s * (1.f / 256.f);
        float dx = v.x - mean, dy = v.y - mean, dz = v.z - mean, dw = v.w - mean;
        float q = dx * dx + dy * dy + dz * dz + dw * dw;
#pragma unroll
        for (int mk = 32; mk; mk >>= 1) q += __shfl_xor(q, mk);
        float rstd = rsqrtf(q * (1.f / 256.f) + 1e-5f);
        int grow = row0 + r;
        float4 p4 = ((const float4*)pos)[(size_t)(grow & (N_ - 1)) * 64 + lane];
        float o0 = dx * rstd * g4.x + b4.x + p4.x;
        float o1 = dy * rstd * g4.y + b4.y + p4.y;
        float o2 = dz * rstd * g4.z + b4.z + p4.z;
        float o3 = dw * rstd * g4.w + b4.w + p4.w;
        ((float4*)(H + (size_t)grow * D_))[lane] = (float4){o0, o1, o2, o3};
        ushort4v u = {f2bf(o0), f2bf(o1), f2bf(o2), f2bf(o3)};
        *((ushort4v*)(Hb + (size_t)grow * D_) + lane) = u;
    }
}

// ---------------------------------------------------------------- fused BN2 + patch + LN + pyr
template <bool DO_PATCH>
__global__ __launch_bounds__(256) void bnpatch_kernel(
    const float* __restrict__ T, const float* __restrict__ bnp,
    const float* __restrict__ bng, const float* __restrict__ bnb,
    const __hip_bfloat16* __restrict__ patchWt, const float* __restrict__ patch_b,
    const float* __restrict__ lng, const float* __restrict__ lnb,
    const float* __restrict__ pos,
    const __hip_bfloat16* __restrict__ pyrWt_l, const float* __restrict__ pyr_b_l,
    int level, float* __restrict__ FLAT,
    float* __restrict__ H, __hip_bfloat16* __restrict__ Hb) {
    __shared__ char __attribute__((aligned(16))) smem[68096];
    float* sm = (float*)(smem + 66048);
    float* sv = sm + 256;
    int tid = threadIdx.x;
    int wid = tid >> 6, lane = tid & 63;
    int row0 = blockIdx.x * 32;
    int r16 = lane & 15, kq = lane >> 4, g = lane >> 4;
    int wr = wid >> 1, wc = wid & 1;

    {
        float s = 0.f, s2 = 0.f;
#pragma unroll 4
        for (int yy = 0; yy < 128; yy++) {
            s += bnp[yy * 256 + tid];
            s2 += bnp[32768 + yy * 256 + tid];
        }
        float m = s * (1.f / 8192.f);
        sm[tid] = m;
        sv[tid] = rsqrtf(s2 * (1.f / 8192.f) - m * m + 1e-5f);
    }
    __syncthreads();
    {
        float4 m4 = ((const float4*)sm)[lane];
        float4 r4 = ((const float4*)sv)[lane];
        float4 g4 = ((const float4*)bng)[lane];
        float4 b4 = ((const float4*)bnb)[lane];
#pragma unroll
        for (int rr = 0; rr < 8; rr++) {
            int r = wid * 8 + rr;
            float4 x4 = ((const float4*)(T + (size_t)(row0 + r) * D_))[lane];
            float o0 = (x4.x - m4.x) * r4.x * g4.x + b4.x;
            float o1 = (x4.y - m4.y) * r4.y * g4.y + b4.y;
            float o2 = (x4.z - m4.z) * r4.z * g4.z + b4.z;
            float o3 = (x4.w - m4.w) * r4.w * g4.w + b4.w;
            ushort4v u = {f2bf(o0), f2bf(o1), f2bf(o2), f2bf(o3)};
            int c = lane >> 1;
            int phys = c ^ (r & 7);
            *(ushort4v*)(smem + r * 512 + phys * 16 + (lane & 1) * 8) = u;
        }
    }
    __syncthreads();

    if (DO_PATCH) {
        f32x4 acc[8];
#pragma unroll
        for (int n = 0; n < 8; n++) acc[n] = (f32x4){0.f, 0.f, 0.f, 0.f};
        for (int k0 = 0; k0 < 256; k0 += 64) {
#pragma unroll
            for (int i = 0; i < 8; i++) {
                int slot = i * 256 + tid;
                int row = slot >> 3, qp = slot & 7;
                int q = qp ^ ((row >> 1) & 7);
                const __hip_bfloat16* gb = patchWt + (size_t)row * 256 + k0 + q * 8;
                __builtin_amdgcn_global_load_lds(
                    (const __attribute__((address_space(1))) void*)gb,
                    (__attribute__((address_space(3))) void*)(smem + 16384 + i * 4096 + wid * 1024),
                    16, 0, 0);
            }
            __syncthreads();
#pragma unroll
            for (int h = 0; h < 2; h++) {
                int arow = wr * 16 + r16;
                int ac = (k0 >> 3) + h * 4 + kq;
                int aphys = ac ^ (arow & 7);
                short8 af = *(const short8*)(smem + arow * 512 + aphys * 16);
                short8 bf4[8];
#pragma unroll
                for (int n = 0; n < 8; n++) {
                    int brow = wc * 128 + n * 16 + r16;
                    int bphys = (h * 4 + kq) ^ ((brow >> 1) & 7);
                    bf4[n] = *(const short8*)(smem + 16384 + brow * 128 + bphys * 16);
                }
#pragma unroll
                for (int n = 0; n < 8; n++)
                    acc[n] = __builtin_amdgcn_mfma_f32_16x16x32_bf16(af, bf4[n], acc[n], 0, 0, 0);
            }
            __syncthreads();
        }
        float (*Cls)[260] = (float(*)[260])(smem + 16384);
#pragma unroll
        for (int n = 0; n < 8; n++) {
            int col = wc * 128 + n * 16 + r16;
            float bv = patch_b[col];
#pragma unroll
            for (int j = 0; j < 4; j++)
                Cls[wr * 16 + g * 4 + j][col] = acc[n][j] + bv;
        }
        __syncthreads();
        float4 g4 = ((const float4*)lng)[lane];
        float4 b4 = ((const float4*)lnb)[lane];
#pragma unroll
        for (int rr = 0; rr < 8; rr++) {
            int r = wid * 8 + rr;
            float4 v = *(const float4*)&Cls[r][lane * 4];
            float s = v.x + v.y + v.z + v.w;
#pragma unroll
            for (int mk = 32; mk; mk >>= 1) s += __shfl_xor(s, mk);
            float mean = s * (1.f / 256.f);
            float dx = v.x - mean, dy = v.y - mean, dz = v.z - mean, dw = v.w - mean;
            float q = dx * dx + dy * dy + dz * dz + dw * dw;
#pragma unroll
            for (int mk = 32; mk; mk >>= 1) q += __shfl_xor(q, mk);
            float rstd = rsqrtf(q * (1.f / 256.f) + 1e-5f);
            int grow = row0 + r;
            float4 p4 = ((const float4*)pos)[(size_t)(grow & (N_ - 1)) * 64 + lane];
            float o0 = dx * rstd * g4.x + b4.x + p4.x;
            float o1 = dy * rstd * g4.y + b4.y + p4.y;
            float o2 = dz * rstd * g4.z + b4.z + p4.z;
            float o3 = dw * rstd * g4.w + b4.w + p4.w;
            ((float4*)(H + (size_t)grow * D_))[lane] = (float4){o0, o1, o2, o3};
            ushort4v u = {f2bf(o0), f2bf(o1), f2bf(o2), f2bf(o3)};
            *((ushort4v*)(Hb + (size_t)grow * D_) + lane) = u;
        }
    }

    f32x4 pacc[4];
#pragma unroll
    for (int n = 0; n < 4; n++) pacc[n] = (f32x4){0.f, 0.f, 0.f, 0.f};
    for (int k0 = 0; k0 < 256; k0 += 64) {
#pragma unroll
        for (int i = 0; i < 4; i++) {
            int slot = i * 256 + tid;
            int row = slot >> 3, qp = slot & 7;
            int q = qp ^ ((row >> 1) & 7);
            const __hip_bfloat16* gb = pyrWt_l + (size_t)row * 256 + k0 + q * 8;
            __builtin_amdgcn_global_load_lds(
                (const __attribute__((address_space(1))) void*)gb,
                (__attribute__((address_space(3))) void*)(smem + 49664 + i * 4096 + wid * 1024),
                16, 0, 0);
        }
        __syncthreads();
#pragma unroll
        for (int h = 0; h < 2; h++) {
            int arow = wr * 16 + r16;
            int ac = (k0 >> 3) + h * 4 + kq;
            int aphys = ac ^ (arow & 7);
            short8 af = *(const short8*)(smem + arow * 512 + aphys * 16);
            short8 bf4[4];
#pragma unroll
            for (int n = 0; n < 4; n++) {
                int brow = wc * 64 + n * 16 + r16;
                int bphys = (h * 4 + kq) ^ ((brow >> 1) & 7);
                bf4[n] = *(const short8*)(smem + 49664 + brow * 128 + bphys * 16);
            }
#pragma unroll
            for (int n = 0; n < 4; n++)
                pacc[n] = __builtin_amdgcn_mfma_f32_16x16x32_bf16(af, bf4[n], pacc[n], 0, 0, 0);
        }
        __syncthreads();
    }
    float (*olds)[33] = (float(*)[33])(smem + 16384);
#pragma unroll
    for (int n = 0; n < 4; n++) {
        int ch = wc * 64 + n * 16 + r16;
        float bv = pyr_b_l[ch];
#pragma unroll
        for (int j = 0; j < 4; j++)
            olds[ch][wr * 16 + g * 4 + j] = pacc[n][j] + bv;
    }
    __syncthreads();
    {
        int ch = tid >> 1, half = tid & 1;
        int bb = row0 >> 9, nn0 = (row0 & 511) + half * 16;
        float* dst = FLAT + (size_t)bb * 327680 + (size_t)(level * 128 + ch) * 512 + nn0;
        const float* src = &olds[ch][half * 16];
#pragma unroll
        for (int q = 0; q < 4; q++)
            *(float4*)(dst + q * 4) = *(const float4*)(src + q * 4);
    }
}

// ---------------------------------------------------------------- MFMA attention
__global__ __launch_bounds__(256) void attn_kernel(
    const __hip_bfloat16* __restrict__ qkv, __hip_bfloat16* __restrict__ outb) {
    int bx = blockIdx.x, h = blockIdx.y, b = blockIdx.z;
    int tid = threadIdx.x;
    int wid = tid >> 6, lane = tid & 63;
    __shared__ __hip_bfloat16 Klds[256 * 32];
    __shared__ __hip_bfloat16 Vt[32 * 264];
    const short* q16 = (const short*)qkv;

#pragma unroll
    for (int r = 0; r < 4; r++) {
        int slot = r * 256 + tid;
        int row = slot >> 2, qp = slot & 3;
        int ql = qp ^ ((row >> 1) & 3);
        int jb = bx * 4 - 2 + (row >> 5);
        jb = jb < 0 ? 0 : (jb > 15 ? 15 : jb);
        const short* ga = q16 + ((size_t)(b * N_ + jb * 32 + (row & 31))) * 768 + 256 + h * 32 + ql * 8;
        __builtin_amdgcn_global_load_lds(
            (const __attribute__((address_space(1))) void*)ga,
            (__attribute__((address_space(3))) void*)((char*)Klds + r * 4096 + wid * 1024),
            16, 0, 0);
    }
    {
        int row = tid;
        int jb = bx * 4 - 2 + (row >> 5);
        jb = jb < 0 ? 0 : (jb > 15 ? 15 : jb);
        const short* gv = q16 + ((size_t)(b * N_ + jb * 32 + (row & 31))) * 768 + 512 + h * 32;
        short8 v0 = *(const short8*)(gv);
        short8 v1 = *(const short8*)(gv + 8);
        short8 v2 = *(const short8*)(gv + 16);
        short8 v3 = *(const short8*)(gv + 24);
        short* vt = (short*)Vt;
#pragma unroll
        for (int e = 0; e < 8; e++) {
            vt[(e) * 264 + row] = v0[e];
            vt[(8 + e) * 264 + row] = v1[e];
            vt[(16 + e) * 264 + row] = v2[e];
            vt[(24 + e) * 264 + row] = v3[e];
        }
    }
    __syncthreads();

    int i = bx * 4 + wid;
    int c = lane & 15, g = lane >> 4;
    const float scale = 0.17677669529663687f;

#pragma unroll
    for (int qt = 0; qt < 2; qt++) {
        const short* qa = q16 + ((size_t)(b * N_ + i * 32 + qt * 16 + c)) * 768 + h * 32 + g * 8;
        short8 bq = *(const short8*)qa;
        f32x4 st[10];
#pragma unroll
        for (int t = 0; t < 10; t++) {
            int jb = i - 2 + (t >> 1);
            if (jb >= 0 && jb < NBLK_) {
                int row = wid * 32 + t * 16 + c;
                int phys = g ^ ((row >> 1) & 3);
                short8 ak = *(const short8*)((const char*)Klds + row * 64 + phys * 16);
                st[t] = __builtin_amdgcn_mfma_f32_16x16x32_bf16(
                    ak, bq, (f32x4){0.f, 0.f, 0.f, 0.f}, 0, 0, 0);
            }
        }
        float mx = -1e30f;
#pragma unroll
        for (int t = 0; t < 10; t++) {
            int jb = i - 2 + (t >> 1);
            if (jb >= 0 && jb < NBLK_) {
#pragma unroll
                for (int j = 0; j < 4; j++) {
                    st[t][j] *= scale;
                    mx = fmaxf(mx, st[t][j]);
                }
            }
        }
        mx = fmaxf(mx, __shfl_xor(mx, 16));
        mx = fmaxf(mx, __shfl_xor(mx, 32));
        float sum = 0.f;
#pragma unroll
        for (int t = 0; t < 10; t++) {
            int jb = i - 2 + (t >> 1);
            if (jb >= 0 && jb < NBLK_) {
#pragma unroll
                for (int j = 0; j < 4; j++) {
                    float e = __expf(st[t][j] - mx);
                    st[t][j] = e;
                    sum += e;
                }
            }
        }
        sum += __shfl_xor(sum, 16);
        sum += __shfl_xor(sum, 32);
        float inv = 1.f / sum;
        f32x4 o0 = (f32x4){0.f, 0.f, 0.f, 0.f};
        f32x4 o1 = (f32x4){0.f, 0.f, 0.f, 0.f};
        const short* vt = (const short*)Vt;
#pragma unroll
        for (int t = 0; t < 10; t++) {
            int jb = i - 2 + (t >> 1);
            if (jb >= 0 && jb < NBLK_) {
                short8 pa = (short8)0;
#pragma unroll
                for (int j = 0; j < 4; j++) pa[j] = (short)f2bf(st[t][j] * inv);
                int kb = wid * 32 + t * 16 + g * 4;
                short4v vb0 = *(const short4v*)(vt + (0 * 16 + c) * 264 + kb);
                short4v vb1 = *(const short4v*)(vt + (1 * 16 + c) * 264 + kb);
                short8 b0 = (short8)0, b1 = (short8)0;
#pragma unroll
                for (int e = 0; e < 4; e++) { b0[e] = vb0[e]; b1[e] = vb1[e]; }
                o0 = __builtin_amdgcn_mfma_f32_16x16x32_bf16(pa, b0, o0, 0, 0, 0);
                o1 = __builtin_amdgcn_mfma_f32_16x16x32_bf16(pa, b1, o1, 0, 0, 0);
            }
        }
#pragma unroll
        for (int j = 0; j < 4; j++) {
            size_t rbase = ((size_t)(b * N_ + i * 32 + qt * 16 + g * 4 + j)) * D_ + h * DH_;
            outb[rbase + c] = __float2bfloat16(o0[j]);
            outb[rbase + 16 + c] = __float2bfloat16(o1[j]);
        }
    }
}

// ---------------------------------------------------------------- fcl
__global__ __launch_bounds__(256) void fcl_partial_kernel(
    const float* __restrict__ flat, const float* __restrict__ W,
    float* __restrict__ partial) {
    int chunk = blockIdx.x;             // 1280
    int t = threadIdx.x;
    int k0 = chunk * FCL_KB;
    __shared__ float fl[FCL_KB][20];
#pragma unroll
    for (int b = 0; b < 16; b++)
        fl[t][b] = flat[(size_t)b * FCL_K + k0 + t];
    __syncthreads();
    int j = t & 127, bg = t >> 7;
    f32x4 a0 = (f32x4){0.f, 0.f, 0.f, 0.f};
    f32x4 a1 = (f32x4){0.f, 0.f, 0.f, 0.f};
#pragma unroll 8
    for (int k = 0; k < FCL_KB; k++) {
        float w = W[(size_t)(k0 + k) * 128 + j];
        f32x4 f0 = *(const f32x4*)&fl[k][bg * 8];
        f32x4 f1 = *(const f32x4*)&fl[k][bg * 8 + 4];
        a0 += f0 * w;
        a1 += f1 * w;
    }
#pragma unroll
    for (int bi = 0; bi < 4; bi++) {
        partial[((size_t)chunk * 16 + bg * 8 + bi) * 128 + j] = a0[bi];
        partial[((size_t)chunk * 16 + bg * 8 + 4 + bi) * 128 + j] = a1[bi];
    }
}

__global__ __launch_bounds__(256) void fcl_reduce_kernel(
    const float* __restrict__ partial, const float* __restrict__ fcl_b,
    float* __restrict__ add) {
    int c0 = blockIdx.x * 32;
    int t = threadIdx.x;
    int ry = t >> 5, cx = t & 31;
    float s = 0.f;
    for (int r = ry; r < FCL_CHUNKS; r += 8)
        s += partial[(size_t)r * 2048 + c0 + cx];
    __shared__ float red[8][32];
    red[ry][cx] = s; __syncthreads();
    if (ry == 0) {
        float tot = 0.f;
#pragma unroll
        for (int q = 0; q < 8; q++) tot += red[q][cx];
        int col = c0 + cx;
        add[col] = tot + fcl_b[col & 127];
    }
}

// ---------------------------------------------------------------- fused head
__global__ __launch_bounds__(256) void head_kernel(
    const float* __restrict__ add, const float* __restrict__ abg, const float* __restrict__ abb,
    const float* __restrict__ cls_W1, const float* __restrict__ cls_b1,
    const float* __restrict__ cls_W2, const float* __restrict__ cls_b2,
    const float* __restrict__ box_W1, const float* __restrict__ box_b1,
    const float* __restrict__ box_W2, const float* __restrict__ box_b2,
    float* __restrict__ out) {
    __shared__ float a2[16][128];
    __shared__ float cm[16][256];
    __shared__ float cls[16][45];
    __shared__ float bmid[16][128];
    __shared__ float smden[16];
    int t = threadIdx.x;
    if (t < 128) {
        float m = 0.f;
#pragma unroll
        for (int b = 0; b < 16; b++) m += add[b * 128 + t];
        m *= (1.f / 16.f);
        float v = 0.f;
#pragma unroll
        for (int b = 0; b < 16; b++) { float d = add[b * 128 + t] - m; v += d * d; }
        v *= (1.f / 16.f);
        float sc = rsqrtf(v + 1e-5f) * abg[t];
#pragma unroll
        for (int b = 0; b < 16; b++) a2[b][t] = (add[b * 128 + t] - m) * sc + abb[t];
    }
    __syncthreads();
    for (int idx = t; idx < 4096; idx += 256) {
        int m = idx >> 8, c = idx & 255;
        float a = cls_b1[c];
        for (int k = 0; k < 128; k++) a += a2[m][k] * cls_W1[k * 256 + c];
        cm[m][c] = fmaxf(a, 0.f);
    }
    for (int idx = t; idx < 2048; idx += 256) {
        int m = idx >> 7, c = idx & 127;
        float a = box_b1[c];
        for (int k = 0; k < 128; k++) a += a2[m][k] * box_W1[k * 128 + c];
        bmid[m][c] = fmaxf(a, 0.f);
    }
    __syncthreads();
    for (int idx = t; idx < 720; idx += 256) {
        int m = idx / 45, c = idx % 45;
        float a = cls_b2[c];
        for (int k = 0; k < 256; k++) a += cm[m][k] * cls_W2[k * 45 + c];
        cls[m][c] = a;
    }
    __syncthreads();
    if (t < 16) {
        float mx = -1e30f;
        for (int c = 0; c < 45; c++) mx = fmaxf(mx, cls[t][c]);
        float s = 0.f;
        for (int c = 0; c < 45; c++) { float e = expf(cls[t][c] - mx); cls[t][c] = e; s += e; }
        smden[t] = s;
    }
    for (int idx = t; idx < 576; idx += 256) {
        int m = idx / 36, c = idx % 36;
        float a = box_b2[c];
        for (int k = 0; k < 128; k++) a += bmid[m][k] * box_W2[k * 36 + c];
        out[m * 81 + (c >> 2) * 9 + 5 + (c & 3)] = a;
    }
    __syncthreads();
    for (int idx = t; idx < 720; idx += 256) {
        int m = idx / 45, c = idx % 45;
        out[m * 81 + (c / 5) * 9 + (c % 5)] = cls[m][c] / smden[m];
    }
}

// ================================================================ launcher
extern "C" void kernel_launch(void* const* d_in, const int* in_sizes, int n_in,
                              void* d_out, int out_size, void* d_ws, size_t ws_size,
                              hipStream_t stream) {
    const float* x_in    = (const float*)d_in[0];
    const float* patch_W = (const float*)d_in[1];
    const float* patch_b = (const float*)d_in[2];
    const float* ln_g    = (const float*)d_in[3];
    const float* ln_b    = (const float*)d_in[4];
    const float* ff_W1   = (const float*)d_in[5];
    const float* ff_b1   = (const float*)d_in[6];
    const float* ff_W2   = (const float*)d_in[7];
    const float* ff_b2   = (const float*)d_in[8];
    const float* Wqkv    = (const float*)d_in[9];
    const float* bqkv    = (const float*)d_in[10];
    const float* Wo      = (const float*)d_in[11];
    const float* bo      = (const float*)d_in[12];
    const float* bn1_g   = (const float*)d_in[13];
    const float* bn1_b   = (const float*)d_in[14];
    const float* bn2_g   = (const float*)d_in[15];
    const float* bn2_b   = (const float*)d_in[16];
    const float* pyr_W   = (const float*)d_in[17];
    const float* pyr_b   = (const float*)d_in[18];
    const float* fcl_W   = (const float*)d_in[19];
    const float* fcl_b   = (const float*)d_in[20];
    const float* addbn_g = (const float*)d_in[21];
    const float* addbn_b = (const float*)d_in[22];
    const float* cls_W1  = (const float*)d_in[23];
    const float* cls_b1  = (const float*)d_in[24];
    const float* cls_W2  = (const float*)d_in[25];
    const float* cls_b2  = (const float*)d_in[26];
    const float* box_W1  = (const float*)d_in[27];
    const float* box_b1  = (const float*)d_in[28];
    const float* box_W2  = (const float*)d_in[29];
    const float* box_b2  = (const float*)d_in[30];
    float* out = (float*)d_out;

    float* ws = (float*)d_ws;
    size_t off = 0;
    float* POS   = ws + off; off += 131072;
    float* H     = ws + off; off += 2097152;
    float* T     = ws + off; off += 2097152;
    float* UNION = ws + off; off += 4194304;   // MIDb bf16 / QKVb bf16
    float* FLAT  = ws + off; off += 5242880;
    float* PART  = ws + off; off += (size_t)FCL_CHUNKS * 2048;
    float* BNP   = ws + off; off += 2 * 32768;
    float* ADD   = ws + off; off += 2048;
    __hip_bfloat16* Hb   = (__hip_bfloat16*)(ws + off); off += 1048576;
    __hip_bfloat16* Tb   = (__hip_bfloat16*)(ws + off); off += 1048576;
    __hip_bfloat16* Xb   = (__hip_bfloat16*)(ws + off); off += 1048576;
    __hip_bfloat16* ATb  = (__hip_bfloat16*)(ws + off); off += 1048576;
    __hip_bfloat16* patchWt = (__hip_bfloat16*)(ws + off); off += 32768;
    __hip_bfloat16* qkvWt   = (__hip_bfloat16*)(ws + off); off += 98304;
    __hip_bfloat16* WoWt    = (__hip_bfloat16*)(ws + off); off += 32768;
    __hip_bfloat16* W1t     = (__hip_bfloat16*)(ws + off); off += 131072;
    __hip_bfloat16* W2t     = (__hip_bfloat16*)(ws + off); off += 131072;
    __hip_bfloat16* pyrWt   = (__hip_bfloat16*)(ws + off); off += 81920;
    __hip_bfloat16* MIDb = (__hip_bfloat16*)UNION;
    __hip_bfloat16* QKVb = (__hip_bfloat16*)UNION;

    prep_kernel<<<2528, 256, 0, stream>>>(
        patch_W, Wqkv, Wo, ff_W1, ff_W2, pyr_W, x_in,
        patchWt, qkvWt, WoWt, W1t, W2t, pyrWt, POS, Xb);

    patchln_kernel<<<256, 256, 0, stream>>>(Xb, patchWt, patch_b, ln_g, ln_b, POS, H, Hb);

    for (int it = 0; it < 5; it++) {
        bgemm_kernel<1, false, true, false, 128, 128><<<dim3(8, 64), 256, 0, stream>>>(
            Hb, W1t, ff_b1, nullptr, nullptr, MIDb, ROWS_, HIDEF_, D_, nullptr);
        bgemm_kernel<0, false, true, false, 64, 64><<<dim3(4, 128), 256, 0, stream>>>(
            MIDb, W2t, ff_b2, nullptr, nullptr, Tb, ROWS_, D_, HIDEF_, nullptr);
        bgemm_kernel<0, false, true, false, 128, 64><<<dim3(12, 64), 256, 0, stream>>>(
            Tb, qkvWt, bqkv, nullptr, nullptr, QKVb, ROWS_, 768, D_, nullptr);
        attn_kernel<<<dim3(4, HEADS_, B_), 256, 0, stream>>>(QKVb, ATb);
        bgemm_kernel<0, true, false, true, 64, 64><<<dim3(4, 128), 256, 0, stream>>>(
            ATb, WoWt, bo, H, T, nullptr, ROWS_, D_, D_, BNP);
        // fused BN1 + FF1b: stats from BNP, BN-apply -> A-LDS, H written by bx==0
        bnff1_kernel<<<dim3(8, 128), 256, 0, stream>>>(
            T, BNP, bn1_g, bn1_b, W1t, ff_b1, H, MIDb);
        bgemm_kernel<0, true, false, true, 64, 64><<<dim3(4, 128), 256, 0, stream>>>(
            MIDb, W2t, ff_b2, H, T, nullptr, ROWS_, D_, HIDEF_, BNP);
        if (it < 4) {
            bnpatch_kernel<true><<<256, 256, 0, stream>>>(
                T, BNP, bn2_g, bn2_b, patchWt, patch_b, ln_g, ln_b, POS,
                pyrWt + (size_t)it * D_ * PYOUT_, pyr_b + it * PYOUT_, it, FLAT, H, Hb);
        } else {
            bnpatch_kernel<false><<<256, 256, 0, stream>>>(
                T, BNP, bn2_g, bn2_b, patchWt, patch_b, ln_g, ln_b, POS,
                pyrWt + (size_t)it * D_ * PYOUT_, pyr_b + it * PYOUT_, it, FLAT, H, Hb);
        }
    }

    fcl_partial_kernel<<<FCL_CHUNKS, 256, 0, stream>>>(FLAT, fcl_W, PART);
    fcl_reduce_kernel<<<64, 256, 0, stream>>>(PART, fcl_b, ADD);
    head_kernel<<<1, 256, 0, stream>>>(ADD, addbn_g, addbn_b,
        cls_W1, cls_b1, cls_W2, cls_b2, box_W1, box_b1, box_W2, box_b2, out);
    (void)in_sizes; (void)n_in; (void)out_size; (void)ws_size;
}

// Round 12
// 866.820 us; speedup vs baseline: 1.0366x; 1.0366x over previous
//
#include <hip/hip_runtime.h>
#include <hip/hip_bf16.h>
#include <math.h>

#define B_ 16
#define N_ 512
#define D_ 256
#define HEADS_ 8
#define DH_ 32
#define HIDEF_ 1024
#define NBLK_ 16
#define BS_ 32
#define LEVELS_ 5
#define PYOUT_ 128
#define ROWS_ (B_ * N_)   // 8192
#define FCL_K 327680
#define FCL_KB 256
#define FCL_CHUNKS 1280

typedef __attribute__((ext_vector_type(8))) short short8;
typedef __attribute__((ext_vector_type(4))) short short4v;
typedef __attribute__((ext_vector_type(4))) unsigned short ushort4v;
typedef __attribute__((ext_vector_type(4))) float f32x4;

__device__ __forceinline__ float bf2f(short u) {
    return __uint_as_float(((unsigned int)(unsigned short)u) << 16);
}
__device__ __forceinline__ unsigned short f2bf(float x) {
    __hip_bfloat16 h = __float2bfloat16(x);
    return *reinterpret_cast<unsigned short*>(&h);
}

__device__ __forceinline__ float gelu_f(float x) {
    float x3 = x * x * x;
    return 0.5f * x * (1.f + tanhf(0.7978845608028654f * (x + 0.044715f * x3)));
}

// ---------------------------------------------------------------- combined prep
__global__ __launch_bounds__(256) void prep_kernel(
    const float* __restrict__ patch_W, const float* __restrict__ Wqkv,
    const float* __restrict__ Wo, const float* __restrict__ ff_W1,
    const float* __restrict__ ff_W2, const float* __restrict__ pyr_W,
    const float* __restrict__ x_in,
    __hip_bfloat16* __restrict__ patchWt, __hip_bfloat16* __restrict__ qkvWt,
    __hip_bfloat16* __restrict__ WoWt, __hip_bfloat16* __restrict__ W1t,
    __hip_bfloat16* __restrict__ W2t, __hip_bfloat16* __restrict__ pyrWt,
    float* __restrict__ pos, __hip_bfloat16* __restrict__ Xb) {
    __shared__ float tt[32][33];
    int bid = blockIdx.x, t = threadIdx.x;
    if (bid >= 1504) {           // x -> bf16, 2048 elems/block
        int base = (bid - 1504) * 2048 + t * 8;
        float4 a = *(const float4*)&x_in[base];
        float4 b = *(const float4*)&x_in[base + 4];
        ushort4v u0 = {f2bf(a.x), f2bf(a.y), f2bf(a.z), f2bf(a.w)};
        ushort4v u1 = {f2bf(b.x), f2bf(b.y), f2bf(b.z), f2bf(b.w)};
        *(ushort4v*)((short*)Xb + base) = u0;
        *(ushort4v*)((short*)Xb + base + 4) = u1;
        return;
    }
    if (bid >= 992) {            // pos table
        int idx = (bid - 992) * 256 + t;
        int n = idx >> 8, i = idx & 255;
        double angle = (double)n / pow(10000.0, (double)(2 * (i >> 1)) / 256.0);
        pos[idx] = (float)((i & 1) ? cos(angle) : sin(angle));
        return;
    }
    const float* W; __hip_bfloat16* Wt; int K, N, bx, by;
    if (bid < 64)       { W = patch_W; Wt = patchWt; K = 256; N = 256; bx = bid % 8; by = bid / 8; }
    else if (bid < 256) { int l = bid - 64;  W = Wqkv;  Wt = qkvWt; K = 256; N = 768;  bx = l % 24; by = l / 24; }
    else if (bid < 320) { int l = bid - 256; W = Wo;    Wt = WoWt;  K = 256; N = 256;  bx = l % 8;  by = l / 8; }
    else if (bid < 576) { int l = bid - 320; W = ff_W1; Wt = W1t;   K = 256; N = 1024; bx = l % 32; by = l / 32; }
    else if (bid < 832) { int l = bid - 576; W = ff_W2; Wt = W2t;   K = 1024; N = 256; bx = l % 8;  by = l / 8; }
    else                { int l = bid - 832; int z = l / 32; int r = l % 32;
                          W = pyr_W + (size_t)z * 256 * 128; Wt = pyrWt + (size_t)z * 256 * 128;
                          K = 256; N = 128; bx = r % 4; by = r / 4; }
    int bx32 = bx * 32, by32 = by * 32;
    int tx = t & 31, ty = t >> 5;
#pragma unroll
    for (int i = 0; i < 32; i += 8)
        tt[ty + i][tx] = W[(size_t)(by32 + ty + i) * N + bx32 + tx];
    __syncthreads();
#pragma unroll
    for (int i = 0; i < 32; i += 8)
        Wt[(size_t)(bx32 + ty + i) * K + by32 + tx] = __float2bfloat16(tt[tx][ty + i]);
}

// ---------------------------------------------------------------- bf16 MFMA GEMM
// BK=64, double-buffered, XCD-aware bijective block swizzle (grids % 8 == 0).
template <int ACT, bool OUTF, bool OUTB, bool STATS, int BM, int BN>
__global__ __launch_bounds__(256) void bgemm_kernel(
    const __hip_bfloat16* __restrict__ A, const __hip_bfloat16* __restrict__ Wt,
    const float* __restrict__ bias, const float* __restrict__ resid,
    float* __restrict__ C, __hip_bfloat16* __restrict__ Cb, int M, int Nn, int K,
    float* __restrict__ bnp) {
    __shared__ __hip_bfloat16 Alds[2][BM * 64];
    __shared__ __hip_bfloat16 Blds[2][BN * 64];
    constexpr int WM_ = (BM == 128 && BN == 64) ? 4 : 2;
    constexpr int WN_ = 4 / WM_;
    constexpr int WH = BM / WM_;
    constexpr int WC = BN / WN_;
    constexpr int MW = WH / 16;
    constexpr int NW = WC / 16;
    constexpr int AR = BM / 32;
    constexpr int BR = BN / 32;
    int tid = threadIdx.x;
    int wid = tid >> 6, lane = tid & 63;
    int flat = blockIdx.y * gridDim.x + blockIdx.x;
    int q8 = (gridDim.x * gridDim.y) >> 3;
    int wg = (flat & 7) * q8 + (flat >> 3);
    int bx = wg % gridDim.x, by = wg / gridDim.x;
    int row0 = by * BM, col0 = bx * BN;
    int wr = wid / WN_, wc = wid % WN_;
    int r16 = lane & 15, kq = lane >> 4;

    f32x4 acc[MW][NW];
#pragma unroll
    for (int m = 0; m < MW; m++)
#pragma unroll
        for (int n = 0; n < NW; n++) acc[m][n] = (f32x4){0.f, 0.f, 0.f, 0.f};

    auto stage = [&](int b, int k0) {
#pragma unroll
        for (int i = 0; i < AR; i++) {
            int slot = i * 256 + tid;
            int row = slot >> 3, qp = slot & 7;
            int q = qp ^ ((row >> 1) & 7);
            const __hip_bfloat16* ga = A + (size_t)(row0 + row) * K + k0 + q * 8;
            __builtin_amdgcn_global_load_lds(
                (const __attribute__((address_space(1))) void*)ga,
                (__attribute__((address_space(3))) void*)((char*)&Alds[b][0] + i * 4096 + wid * 1024),
                16, 0, 0);
        }
#pragma unroll
        for (int i = 0; i < BR; i++) {
            int slot = i * 256 + tid;
            int row = slot >> 3, qp = slot & 7;
            int q = qp ^ ((row >> 1) & 7);
            const __hip_bfloat16* gb = Wt + (size_t)(col0 + row) * K + k0 + q * 8;
            __builtin_amdgcn_global_load_lds(
                (const __attribute__((address_space(1))) void*)gb,
                (__attribute__((address_space(3))) void*)((char*)&Blds[b][0] + i * 4096 + wid * 1024),
                16, 0, 0);
        }
    };

    stage(0, 0);
    __syncthreads();
    int cur = 0;
    for (int k0 = 0; k0 < K; k0 += 64) {
        if (k0 + 64 < K) stage(cur ^ 1, k0 + 64);
#pragma unroll
        for (int h = 0; h < 2; h++) {
            short8 af[MW], bf4[NW];
#pragma unroll
            for (int m = 0; m < MW; m++) {
                int row = wr * WH + m * 16 + r16;
                int phys = (h * 4 + kq) ^ ((row >> 1) & 7);
                af[m] = *reinterpret_cast<const short8*>(
                    reinterpret_cast<const char*>(&Alds[cur][0]) + row * 128 + phys * 16);
            }
#pragma unroll
            for (int n = 0; n < NW; n++) {
                int row = wc * WC + n * 16 + r16;
                int phys = (h * 4 + kq) ^ ((row >> 1) & 7);
                bf4[n] = *reinterpret_cast<const short8*>(
                    reinterpret_cast<const char*>(&Blds[cur][0]) + row * 128 + phys * 16);
            }
#pragma unroll
            for (int m = 0; m < MW; m++)
#pragma unroll
                for (int n = 0; n < NW; n++)
                    acc[m][n] = __builtin_amdgcn_mfma_f32_16x16x32_bf16(af[m], bf4[n], acc[m][n], 0, 0, 0);
        }
        __syncthreads();
        cur ^= 1;
    }

    int rg = lane >> 4;
    float s1a[NW], s2a[NW];
#pragma unroll
    for (int n = 0; n < NW; n++) { s1a[n] = 0.f; s2a[n] = 0.f; }
#pragma unroll
    for (int n = 0; n < NW; n++) {
        int cc = col0 + wc * WC + n * 16 + r16;
        float bv = bias[cc];
#pragma unroll
        for (int m = 0; m < MW; m++) {
            int rb = row0 + wr * WH + m * 16 + rg * 4;
#pragma unroll
            for (int j = 0; j < 4; j++) {
                int r = rb + j;
                float v = acc[m][n][j] + bv;
                if (resid) v += resid[(size_t)r * Nn + cc];
                if (ACT == 1) v = gelu_f(v);
                if (OUTF) C[(size_t)r * Nn + cc] = v;
                if (OUTB) Cb[(size_t)r * Nn + cc] = __float2bfloat16(v);
                if (STATS) { s1a[n] += v; s2a[n] += v * v; }
            }
        }
    }
    if (STATS) {
        float* sc = (float*)&Alds[0][0];
        int part = wid * 4 + rg;
#pragma unroll
        for (int n = 0; n < NW; n++) {
            int c = wc * WC + n * 16 + r16;
            sc[c * 16 + part] = s1a[n];
            sc[BN * 16 + c * 16 + part] = s2a[n];
        }
        __syncthreads();
        if (tid < BN) {
            float a = 0.f, b2 = 0.f;
#pragma unroll
            for (int p = 0; p < 16; p++) {
                a += sc[tid * 16 + p];
                b2 += sc[BN * 16 + tid * 16 + p];
            }
            bnp[by * 256 + col0 + tid] = a;
            bnp[32768 + by * 256 + col0 + tid] = b2;
        }
    }
}

// ---------------------------------------------------------------- patchln (it=0 only)
__global__ __launch_bounds__(256) void patchln_kernel(
    const __hip_bfloat16* __restrict__ A, const __hip_bfloat16* __restrict__ Wt,
    const float* __restrict__ bias, const float* __restrict__ lng,
    const float* __restrict__ lnb, const float* __restrict__ pos,
    float* __restrict__ H, __hip_bfloat16* __restrict__ Hb) {
    __shared__ char __attribute__((aligned(16))) smem[73728];
    float (*Cls)[260] = (float(*)[260])smem;
    int tid = threadIdx.x;
    int wid = tid >> 6, lane = tid & 63;
    int row0 = blockIdx.x * 32;
    int r16 = lane & 15, kq = lane >> 4, g = lane >> 4;

    f32x4 acc[2][4];
#pragma unroll
    for (int m = 0; m < 2; m++)
#pragma unroll
        for (int n = 0; n < 4; n++) acc[m][n] = (f32x4){0.f, 0.f, 0.f, 0.f};

    auto stage = [&](int b, int k0) {
        {
            int row = tid >> 3, qp = tid & 7;
            int q = qp ^ ((row >> 1) & 7);
            const __hip_bfloat16* ga = A + (size_t)(row0 + row) * 256 + k0 + q * 8;
            __builtin_amdgcn_global_load_lds(
                (const __attribute__((address_space(1))) void*)ga,
                (__attribute__((address_space(3))) void*)(smem + b * 4096 + wid * 1024),
                16, 0, 0);
        }
#pragma unroll
        for (int i = 0; i < 8; i++) {
            int slot = i * 256 + tid;
            int row = slot >> 3, qp = slot & 7;
            int q = qp ^ ((row >> 1) & 7);
            const __hip_bfloat16* gb = Wt + (size_t)row * 256 + k0 + q * 8;
            __builtin_amdgcn_global_load_lds(
                (const __attribute__((address_space(1))) void*)gb,
                (__attribute__((address_space(3))) void*)(smem + 8192 + b * 32768 + i * 4096 + wid * 1024),
                16, 0, 0);
        }
    };

    stage(0, 0);
    __syncthreads();
    int cur = 0;
    for (int k0 = 0; k0 < 256; k0 += 64) {
        if (k0 + 64 < 256) stage(cur ^ 1, k0 + 64);
        const char* Ab = smem + cur * 4096;
        const char* Bb = smem + 8192 + cur * 32768;
#pragma unroll
        for (int h = 0; h < 2; h++) {
            short8 af[2], bf4[4];
#pragma unroll
            for (int m = 0; m < 2; m++) {
                int row = m * 16 + r16;
                int phys = (h * 4 + kq) ^ ((row >> 1) & 7);
                af[m] = *reinterpret_cast<const short8*>(Ab + row * 128 + phys * 16);
            }
#pragma unroll
            for (int n = 0; n < 4; n++) {
                int row = wid * 64 + n * 16 + r16;
                int phys = (h * 4 + kq) ^ ((row >> 1) & 7);
                bf4[n] = *reinterpret_cast<const short8*>(Bb + row * 128 + phys * 16);
            }
#pragma unroll
            for (int m = 0; m < 2; m++)
#pragma unroll
                for (int n = 0; n < 4; n++)
                    acc[m][n] = __builtin_amdgcn_mfma_f32_16x16x32_bf16(af[m], bf4[n], acc[m][n], 0, 0, 0);
        }
        __syncthreads();
        cur ^= 1;
    }
#pragma unroll
    for (int n = 0; n < 4; n++) {
        int col = wid * 64 + n * 16 + r16;
        float bv = bias[col];
#pragma unroll
        for (int m = 0; m < 2; m++)
#pragma unroll
            for (int j = 0; j < 4; j++)
                Cls[m * 16 + g * 4 + j][col] = acc[m][n][j] + bv;
    }
    __syncthreads();
    float4 g4 = ((const float4*)lng)[lane];
    float4 b4 = ((const float4*)lnb)[lane];
#pragma unroll
    for (int rr = 0; rr < 8; rr++) {
        int r = wid * 8 + rr;
        float4 v = *(const float4*)&Cls[r][lane * 4];
        float s = v.x + v.y + v.z + v.w;
#pragma unroll
        for (int mk = 32; mk; mk >>= 1) s += __shfl_xor(s, mk);
        float mean = s * (1.f / 256.f);
        float dx = v.x - mean, dy = v.y - mean, dz = v.z - mean, dw = v.w - mean;
        float q = dx * dx + dy * dy + dz * dz + dw * dw;
#pragma unroll
        for (int mk = 32; mk; mk >>= 1) q += __shfl_xor(q, mk);
        float rstd = rsqrtf(q * (1.f / 256.f) + 1e-5f);
        int grow = row0 + r;
        float4 p4 = ((const float4*)pos)[(size_t)(grow & (N_ - 1)) * 64 + lane];
        float o0 = dx * rstd * g4.x + b4.x + p4.x;
        float o1 = dy * rstd * g4.y + b4.y + p4.y;
        float o2 = dz * rstd * g4.z + b4.z + p4.z;
        float o3 = dw * rstd * g4.w + b4.w + p4.w;
        ((float4*)(H + (size_t)grow * D_))[lane] = (float4){o0, o1, o2, o3};
        ushort4v u = {f2bf(o0), f2bf(o1), f2bf(o2), f2bf(o3)};
        *((ushort4v*)(Hb + (size_t)grow * D_) + lane) = u;
    }
}

// ---------------------------------------------------------------- fused BN2 + patch + LN + pyr
template <bool DO_PATCH>
__global__ __launch_bounds__(256) void bnpatch_kernel(
    const float* __restrict__ T, const float* __restrict__ bnp,
    const float* __restrict__ bng, const float* __restrict__ bnb,
    const __hip_bfloat16* __restrict__ patchWt, const float* __restrict__ patch_b,
    const float* __restrict__ lng, const float* __restrict__ lnb,
    const float* __restrict__ pos,
    const __hip_bfloat16* __restrict__ pyrWt_l, const float* __restrict__ pyr_b_l,
    int level, float* __restrict__ FLAT,
    float* __restrict__ H, __hip_bfloat16* __restrict__ Hb) {
    __shared__ char __attribute__((aligned(16))) smem[68096];
    float* sm = (float*)(smem + 66048);
    float* sv = sm + 256;
    int tid = threadIdx.x;
    int wid = tid >> 6, lane = tid & 63;
    int row0 = blockIdx.x * 32;
    int r16 = lane & 15, kq = lane >> 4, g = lane >> 4;
    int wr = wid >> 1, wc = wid & 1;

    {
        float s = 0.f, s2 = 0.f;
#pragma unroll 4
        for (int yy = 0; yy < 128; yy++) {
            s += bnp[yy * 256 + tid];
            s2 += bnp[32768 + yy * 256 + tid];
        }
        float m = s * (1.f / 8192.f);
        sm[tid] = m;
        sv[tid] = rsqrtf(s2 * (1.f / 8192.f) - m * m + 1e-5f);
    }
    __syncthreads();
    {
        float4 m4 = ((const float4*)sm)[lane];
        float4 r4 = ((const float4*)sv)[lane];
        float4 g4 = ((const float4*)bng)[lane];
        float4 b4 = ((const float4*)bnb)[lane];
#pragma unroll
        for (int rr = 0; rr < 8; rr++) {
            int r = wid * 8 + rr;
            float4 x4 = ((const float4*)(T + (size_t)(row0 + r) * D_))[lane];
            float o0 = (x4.x - m4.x) * r4.x * g4.x + b4.x;
            float o1 = (x4.y - m4.y) * r4.y * g4.y + b4.y;
            float o2 = (x4.z - m4.z) * r4.z * g4.z + b4.z;
            float o3 = (x4.w - m4.w) * r4.w * g4.w + b4.w;
            ushort4v u = {f2bf(o0), f2bf(o1), f2bf(o2), f2bf(o3)};
            int c = lane >> 1;
            int phys = c ^ (r & 7);
            *(ushort4v*)(smem + r * 512 + phys * 16 + (lane & 1) * 8) = u;
        }
    }
    __syncthreads();

    if (DO_PATCH) {
        f32x4 acc[8];
#pragma unroll
        for (int n = 0; n < 8; n++) acc[n] = (f32x4){0.f, 0.f, 0.f, 0.f};
        for (int k0 = 0; k0 < 256; k0 += 64) {
#pragma unroll
            for (int i = 0; i < 8; i++) {
                int slot = i * 256 + tid;
                int row = slot >> 3, qp = slot & 7;
                int q = qp ^ ((row >> 1) & 7);
                const __hip_bfloat16* gb = patchWt + (size_t)row * 256 + k0 + q * 8;
                __builtin_amdgcn_global_load_lds(
                    (const __attribute__((address_space(1))) void*)gb,
                    (__attribute__((address_space(3))) void*)(smem + 16384 + i * 4096 + wid * 1024),
                    16, 0, 0);
            }
            __syncthreads();
#pragma unroll
            for (int h = 0; h < 2; h++) {
                int arow = wr * 16 + r16;
                int ac = (k0 >> 3) + h * 4 + kq;
                int aphys = ac ^ (arow & 7);
                short8 af = *(const short8*)(smem + arow * 512 + aphys * 16);
                short8 bf4[8];
#pragma unroll
                for (int n = 0; n < 8; n++) {
                    int brow = wc * 128 + n * 16 + r16;
                    int bphys = (h * 4 + kq) ^ ((brow >> 1) & 7);
                    bf4[n] = *(const short8*)(smem + 16384 + brow * 128 + bphys * 16);
                }
#pragma unroll
                for (int n = 0; n < 8; n++)
                    acc[n] = __builtin_amdgcn_mfma_f32_16x16x32_bf16(af, bf4[n], acc[n], 0, 0, 0);
            }
            __syncthreads();
        }
        float (*Cls)[260] = (float(*)[260])(smem + 16384);
#pragma unroll
        for (int n = 0; n < 8; n++) {
            int col = wc * 128 + n * 16 + r16;
            float bv = patch_b[col];
#pragma unroll
            for (int j = 0; j < 4; j++)
                Cls[wr * 16 + g * 4 + j][col] = acc[n][j] + bv;
        }
        __syncthreads();
        float4 g4 = ((const float4*)lng)[lane];
        float4 b4 = ((const float4*)lnb)[lane];
#pragma unroll
        for (int rr = 0; rr < 8; rr++) {
            int r = wid * 8 + rr;
            float4 v = *(const float4*)&Cls[r][lane * 4];
            float s = v.x + v.y + v.z + v.w;
#pragma unroll
            for (int mk = 32; mk; mk >>= 1) s += __shfl_xor(s, mk);
            float mean = s * (1.f / 256.f);
            float dx = v.x - mean, dy = v.y - mean, dz = v.z - mean, dw = v.w - mean;
            float q = dx * dx + dy * dy + dz * dz + dw * dw;
#pragma unroll
            for (int mk = 32; mk; mk >>= 1) q += __shfl_xor(q, mk);
            float rstd = rsqrtf(q * (1.f / 256.f) + 1e-5f);
            int grow = row0 + r;
            float4 p4 = ((const float4*)pos)[(size_t)(grow & (N_ - 1)) * 64 + lane];
            float o0 = dx * rstd * g4.x + b4.x + p4.x;
            float o1 = dy * rstd * g4.y + b4.y + p4.y;
            float o2 = dz * rstd * g4.z + b4.z + p4.z;
            float o3 = dw * rstd * g4.w + b4.w + p4.w;
            ((float4*)(H + (size_t)grow * D_))[lane] = (float4){o0, o1, o2, o3};
            ushort4v u = {f2bf(o0), f2bf(o1), f2bf(o2), f2bf(o3)};
            *((ushort4v*)(Hb + (size_t)grow * D_) + lane) = u;
        }
    }

    f32x4 pacc[4];
#pragma unroll
    for (int n = 0; n < 4; n++) pacc[n] = (f32x4){0.f, 0.f, 0.f, 0.f};
    for (int k0 = 0; k0 < 256; k0 += 64) {
#pragma unroll
        for (int i = 0; i < 4; i++) {
            int slot = i * 256 + tid;
            int row = slot >> 3, qp = slot & 7;
            int q = qp ^ ((row >> 1) & 7);
            const __hip_bfloat16* gb = pyrWt_l + (size_t)row * 256 + k0 + q * 8;
            __builtin_amdgcn_global_load_lds(
                (const __attribute__((address_space(1))) void*)gb,
                (__attribute__((address_space(3))) void*)(smem + 49664 + i * 4096 + wid * 1024),
                16, 0, 0);
        }
        __syncthreads();
#pragma unroll
        for (int h = 0; h < 2; h++) {
            int arow = wr * 16 + r16;
            int ac = (k0 >> 3) + h * 4 + kq;
            int aphys = ac ^ (arow & 7);
            short8 af = *(const short8*)(smem + arow * 512 + aphys * 16);
            short8 bf4[4];
#pragma unroll
            for (int n = 0; n < 4; n++) {
                int brow = wc * 64 + n * 16 + r16;
                int bphys = (h * 4 + kq) ^ ((brow >> 1) & 7);
                bf4[n] = *(const short8*)(smem + 49664 + brow * 128 + bphys * 16);
            }
#pragma unroll
            for (int n = 0; n < 4; n++)
                pacc[n] = __builtin_amdgcn_mfma_f32_16x16x32_bf16(af, bf4[n], pacc[n], 0, 0, 0);
        }
        __syncthreads();
    }
    float (*olds)[33] = (float(*)[33])(smem + 16384);
#pragma unroll
    for (int n = 0; n < 4; n++) {
        int ch = wc * 64 + n * 16 + r16;
        float bv = pyr_b_l[ch];
#pragma unroll
        for (int j = 0; j < 4; j++)
            olds[ch][wr * 16 + g * 4 + j] = pacc[n][j] + bv;
    }
    __syncthreads();
    {
        int ch = tid >> 1, half = tid & 1;
        int bb = row0 >> 9, nn0 = (row0 & 511) + half * 16;
        float* dst = FLAT + (size_t)bb * 327680 + (size_t)(level * 128 + ch) * 512 + nn0;
        const float* src = &olds[ch][half * 16];
#pragma unroll
        for (int q = 0; q < 4; q++)
            *(float4*)(dst + q * 4) = *(const float4*)(src + q * 4);
    }
}

// ---------------------------------------------------------------- BN finish+apply (bn1)
__global__ __launch_bounds__(256) void bn_applyfin_kernel(
    const float* __restrict__ x, const float* __restrict__ bnp, int prows,
    const float* __restrict__ g, const float* __restrict__ b,
    float* __restrict__ y, __hip_bfloat16* __restrict__ yb) {
    int tid = threadIdx.x;
    __shared__ float sm[256], sv[256];
    {
        float s = 0.f, s2 = 0.f;
#pragma unroll 4
        for (int yy = 0; yy < prows; yy++) {
            s += bnp[yy * 256 + tid];
            s2 += bnp[32768 + yy * 256 + tid];
        }
        float m = s * (1.f / 8192.f);
        sm[tid] = m;
        sv[tid] = rsqrtf(s2 * (1.f / 8192.f) - m * m + 1e-5f);
    }
    __syncthreads();
    int lane = tid & 63, w = tid >> 6;
    int row0 = blockIdx.x * 32;
    float4 m4 = *(const float4*)&sm[lane * 4];
    float4 r4 = *(const float4*)&sv[lane * 4];
    float4 g4 = ((const float4*)g)[lane];
    float4 b4 = ((const float4*)b)[lane];
#pragma unroll
    for (int rr = 0; rr < 8; rr++) {
        int row = row0 + w * 8 + rr;
        float4 x4 = ((const float4*)(x + (size_t)row * D_))[lane];
        float o0 = (x4.x - m4.x) * r4.x * g4.x + b4.x;
        float o1 = (x4.y - m4.y) * r4.y * g4.y + b4.y;
        float o2 = (x4.z - m4.z) * r4.z * g4.z + b4.z;
        float o3 = (x4.w - m4.w) * r4.w * g4.w + b4.w;
        if (y) ((float4*)(y + (size_t)row * D_))[lane] = (float4){o0, o1, o2, o3};
        if (yb) {
            ushort4v u = {f2bf(o0), f2bf(o1), f2bf(o2), f2bf(o3)};
            *((ushort4v*)(yb + (size_t)row * D_) + lane) = u;
        }
    }
}

// ---------------------------------------------------------------- MFMA attention
__global__ __launch_bounds__(256) void attn_kernel(
    const __hip_bfloat16* __restrict__ qkv, __hip_bfloat16* __restrict__ outb) {
    int bx = blockIdx.x, h = blockIdx.y, b = blockIdx.z;
    int tid = threadIdx.x;
    int wid = tid >> 6, lane = tid & 63;
    __shared__ __hip_bfloat16 Klds[256 * 32];
    __shared__ __hip_bfloat16 Vt[32 * 264];
    const short* q16 = (const short*)qkv;

#pragma unroll
    for (int r = 0; r < 4; r++) {
        int slot = r * 256 + tid;
        int row = slot >> 2, qp = slot & 3;
        int ql = qp ^ ((row >> 1) & 3);
        int jb = bx * 4 - 2 + (row >> 5);
        jb = jb < 0 ? 0 : (jb > 15 ? 15 : jb);
        const short* ga = q16 + ((size_t)(b * N_ + jb * 32 + (row & 31))) * 768 + 256 + h * 32 + ql * 8;
        __builtin_amdgcn_global_load_lds(
            (const __attribute__((address_space(1))) void*)ga,
            (__attribute__((address_space(3))) void*)((char*)Klds + r * 4096 + wid * 1024),
            16, 0, 0);
    }
    {
        int row = tid;
        int jb = bx * 4 - 2 + (row >> 5);
        jb = jb < 0 ? 0 : (jb > 15 ? 15 : jb);
        const short* gv = q16 + ((size_t)(b * N_ + jb * 32 + (row & 31))) * 768 + 512 + h * 32;
        short8 v0 = *(const short8*)(gv);
        short8 v1 = *(const short8*)(gv + 8);
        short8 v2 = *(const short8*)(gv + 16);
        short8 v3 = *(const short8*)(gv + 24);
        short* vt = (short*)Vt;
#pragma unroll
        for (int e = 0; e < 8; e++) {
            vt[(e) * 264 + row] = v0[e];
            vt[(8 + e) * 264 + row] = v1[e];
            vt[(16 + e) * 264 + row] = v2[e];
            vt[(24 + e) * 264 + row] = v3[e];
        }
    }
    __syncthreads();

    int i = bx * 4 + wid;
    int c = lane & 15, g = lane >> 4;
    const float scale = 0.17677669529663687f;

#pragma unroll
    for (int qt = 0; qt < 2; qt++) {
        const short* qa = q16 + ((size_t)(b * N_ + i * 32 + qt * 16 + c)) * 768 + h * 32 + g * 8;
        short8 bq = *(const short8*)qa;
        f32x4 st[10];
#pragma unroll
        for (int t = 0; t < 10; t++) {
            int jb = i - 2 + (t >> 1);
            if (jb >= 0 && jb < NBLK_) {
                int row = wid * 32 + t * 16 + c;
                int phys = g ^ ((row >> 1) & 3);
                short8 ak = *(const short8*)((const char*)Klds + row * 64 + phys * 16);
                st[t] = __builtin_amdgcn_mfma_f32_16x16x32_bf16(
                    ak, bq, (f32x4){0.f, 0.f, 0.f, 0.f}, 0, 0, 0);
            }
        }
        float mx = -1e30f;
#pragma unroll
        for (int t = 0; t < 10; t++) {
            int jb = i - 2 + (t >> 1);
            if (jb >= 0 && jb < NBLK_) {
#pragma unroll
                for (int j = 0; j < 4; j++) {
                    st[t][j] *= scale;
                    mx = fmaxf(mx, st[t][j]);
                }
            }
        }
        mx = fmaxf(mx, __shfl_xor(mx, 16));
        mx = fmaxf(mx, __shfl_xor(mx, 32));
        float sum = 0.f;
#pragma unroll
        for (int t = 0; t < 10; t++) {
            int jb = i - 2 + (t >> 1);
            if (jb >= 0 && jb < NBLK_) {
#pragma unroll
                for (int j = 0; j < 4; j++) {
                    float e = __expf(st[t][j] - mx);
                    st[t][j] = e;
                    sum += e;
                }
            }
        }
        sum += __shfl_xor(sum, 16);
        sum += __shfl_xor(sum, 32);
        float inv = 1.f / sum;
        f32x4 o0 = (f32x4){0.f, 0.f, 0.f, 0.f};
        f32x4 o1 = (f32x4){0.f, 0.f, 0.f, 0.f};
        const short* vt = (const short*)Vt;
#pragma unroll
        for (int t = 0; t < 10; t++) {
            int jb = i - 2 + (t >> 1);
            if (jb >= 0 && jb < NBLK_) {
                short8 pa = (short8)0;
#pragma unroll
                for (int j = 0; j < 4; j++) pa[j] = (short)f2bf(st[t][j] * inv);
                int kb = wid * 32 + t * 16 + g * 4;
                short4v vb0 = *(const short4v*)(vt + (0 * 16 + c) * 264 + kb);
                short4v vb1 = *(const short4v*)(vt + (1 * 16 + c) * 264 + kb);
                short8 b0 = (short8)0, b1 = (short8)0;
#pragma unroll
                for (int e = 0; e < 4; e++) { b0[e] = vb0[e]; b1[e] = vb1[e]; }
                o0 = __builtin_amdgcn_mfma_f32_16x16x32_bf16(pa, b0, o0, 0, 0, 0);
                o1 = __builtin_amdgcn_mfma_f32_16x16x32_bf16(pa, b1, o1, 0, 0, 0);
            }
        }
#pragma unroll
        for (int j = 0; j < 4; j++) {
            size_t rbase = ((size_t)(b * N_ + i * 32 + qt * 16 + g * 4 + j)) * D_ + h * DH_;
            outb[rbase + c] = __float2bfloat16(o0[j]);
            outb[rbase + 16 + c] = __float2bfloat16(o1[j]);
        }
    }
}

// ---------------------------------------------------------------- fcl
__global__ __launch_bounds__(256) void fcl_partial_kernel(
    const float* __restrict__ flat, const float* __restrict__ W,
    float* __restrict__ partial) {
    int chunk = blockIdx.x;             // 1280
    int t = threadIdx.x;
    int k0 = chunk * FCL_KB;
    __shared__ float fl[FCL_KB][20];
#pragma unroll
    for (int b = 0; b < 16; b++)
        fl[t][b] = flat[(size_t)b * FCL_K + k0 + t];
    __syncthreads();
    int j = t & 127, bg = t >> 7;
    f32x4 a0 = (f32x4){0.f, 0.f, 0.f, 0.f};
    f32x4 a1 = (f32x4){0.f, 0.f, 0.f, 0.f};
#pragma unroll 8
    for (int k = 0; k < FCL_KB; k++) {
        float w = W[(size_t)(k0 + k) * 128 + j];
        f32x4 f0 = *(const f32x4*)&fl[k][bg * 8];
        f32x4 f1 = *(const f32x4*)&fl[k][bg * 8 + 4];
        a0 += f0 * w;
        a1 += f1 * w;
    }
#pragma unroll
    for (int bi = 0; bi < 4; bi++) {
        partial[((size_t)chunk * 16 + bg * 8 + bi) * 128 + j] = a0[bi];
        partial[((size_t)chunk * 16 + bg * 8 + 4 + bi) * 128 + j] = a1[bi];
    }
}

__global__ __launch_bounds__(256) void fcl_reduce_kernel(
    const float* __restrict__ partial, const float* __restrict__ fcl_b,
    float* __restrict__ add) {
    int c0 = blockIdx.x * 32;
    int t = threadIdx.x;
    int ry = t >> 5, cx = t & 31;
    float s = 0.f;
    for (int r = ry; r < FCL_CHUNKS; r += 8)
        s += partial[(size_t)r * 2048 + c0 + cx];
    __shared__ float red[8][32];
    red[ry][cx] = s; __syncthreads();
    if (ry == 0) {
        float tot = 0.f;
#pragma unroll
        for (int q = 0; q < 8; q++) tot += red[q][cx];
        int col = c0 + cx;
        add[col] = tot + fcl_b[col & 127];
    }
}

// ---------------------------------------------------------------- fused head
__global__ __launch_bounds__(256) void head_kernel(
    const float* __restrict__ add, const float* __restrict__ abg, const float* __restrict__ abb,
    const float* __restrict__ cls_W1, const float* __restrict__ cls_b1,
    const float* __restrict__ cls_W2, const float* __restrict__ cls_b2,
    const float* __restrict__ box_W1, const float* __restrict__ box_b1,
    const float* __restrict__ box_W2, const float* __restrict__ box_b2,
    float* __restrict__ out) {
    __shared__ float a2[16][128];
    __shared__ float cm[16][256];
    __shared__ float cls[16][45];
    __shared__ float bmid[16][128];
    __shared__ float smden[16];
    int t = threadIdx.x;
    if (t < 128) {
        float m = 0.f;
#pragma unroll
        for (int b = 0; b < 16; b++) m += add[b * 128 + t];
        m *= (1.f / 16.f);
        float v = 0.f;
#pragma unroll
        for (int b = 0; b < 16; b++) { float d = add[b * 128 + t] - m; v += d * d; }
        v *= (1.f / 16.f);
        float sc = rsqrtf(v + 1e-5f) * abg[t];
#pragma unroll
        for (int b = 0; b < 16; b++) a2[b][t] = (add[b * 128 + t] - m) * sc + abb[t];
    }
    __syncthreads();
    for (int idx = t; idx < 4096; idx += 256) {
        int m = idx >> 8, c = idx & 255;
        float a = cls_b1[c];
        for (int k = 0; k < 128; k++) a += a2[m][k] * cls_W1[k * 256 + c];
        cm[m][c] = fmaxf(a, 0.f);
    }
    for (int idx = t; idx < 2048; idx += 256) {
        int m = idx >> 7, c = idx & 127;
        float a = box_b1[c];
        for (int k = 0; k < 128; k++) a += a2[m][k] * box_W1[k * 128 + c];
        bmid[m][c] = fmaxf(a, 0.f);
    }
    __syncthreads();
    for (int idx = t; idx < 720; idx += 256) {
        int m = idx / 45, c = idx % 45;
        float a = cls_b2[c];
        for (int k = 0; k < 256; k++) a += cm[m][k] * cls_W2[k * 45 + c];
        cls[m][c] = a;
    }
    __syncthreads();
    if (t < 16) {
        float mx = -1e30f;
        for (int c = 0; c < 45; c++) mx = fmaxf(mx, cls[t][c]);
        float s = 0.f;
        for (int c = 0; c < 45; c++) { float e = expf(cls[t][c] - mx); cls[t][c] = e; s += e; }
        smden[t] = s;
    }
    for (int idx = t; idx < 576; idx += 256) {
        int m = idx / 36, c = idx % 36;
        float a = box_b2[c];
        for (int k = 0; k < 128; k++) a += bmid[m][k] * box_W2[k * 36 + c];
        out[m * 81 + (c >> 2) * 9 + 5 + (c & 3)] = a;
    }
    __syncthreads();
    for (int idx = t; idx < 720; idx += 256) {
        int m = idx / 45, c = idx % 45;
        out[m * 81 + (c / 5) * 9 + (c % 5)] = cls[m][c] / smden[m];
    }
}

// ================================================================ launcher
extern "C" void kernel_launch(void* const* d_in, const int* in_sizes, int n_in,
                              void* d_out, int out_size, void* d_ws, size_t ws_size,
                              hipStream_t stream) {
    const float* x_in    = (const float*)d_in[0];
    const float* patch_W = (const float*)d_in[1];
    const float* patch_b = (const float*)d_in[2];
    const float* ln_g    = (const float*)d_in[3];
    const float* ln_b    = (const float*)d_in[4];
    const float* ff_W1   = (const float*)d_in[5];
    const float* ff_b1   = (const float*)d_in[6];
    const float* ff_W2   = (const float*)d_in[7];
    const float* ff_b2   = (const float*)d_in[8];
    const float* Wqkv    = (const float*)d_in[9];
    const float* bqkv    = (const float*)d_in[10];
    const float* Wo      = (const float*)d_in[11];
    const float* bo      = (const float*)d_in[12];
    const float* bn1_g   = (const float*)d_in[13];
    const float* bn1_b   = (const float*)d_in[14];
    const float* bn2_g   = (const float*)d_in[15];
    const float* bn2_b   = (const float*)d_in[16];
    const float* pyr_W   = (const float*)d_in[17];
    const float* pyr_b   = (const float*)d_in[18];
    const float* fcl_W   = (const float*)d_in[19];
    const float* fcl_b   = (const float*)d_in[20];
    const float* addbn_g = (const float*)d_in[21];
    const float* addbn_b = (const float*)d_in[22];
    const float* cls_W1  = (const float*)d_in[23];
    const float* cls_b1  = (const float*)d_in[24];
    const float* cls_W2  = (const float*)d_in[25];
    const float* cls_b2  = (const float*)d_in[26];
    const float* box_W1  = (const float*)d_in[27];
    const float* box_b1  = (const float*)d_in[28];
    const float* box_W2  = (const float*)d_in[29];
    const float* box_b2  = (const float*)d_in[30];
    float* out = (float*)d_out;

    float* ws = (float*)d_ws;
    size_t off = 0;
    float* POS   = ws + off; off += 131072;
    float* H     = ws + off; off += 2097152;
    float* T     = ws + off; off += 2097152;
    float* UNION = ws + off; off += 4194304;   // MIDb bf16 / QKVb bf16
    float* FLAT  = ws + off; off += 5242880;
    float* PART  = ws + off; off += (size_t)FCL_CHUNKS * 2048;
    float* BNP   = ws + off; off += 2 * 32768;
    float* ADD   = ws + off; off += 2048;
    __hip_bfloat16* Hb   = (__hip_bfloat16*)(ws + off); off += 1048576;
    __hip_bfloat16* Tb   = (__hip_bfloat16*)(ws + off); off += 1048576;
    __hip_bfloat16* Xb   = (__hip_bfloat16*)(ws + off); off += 1048576;
    __hip_bfloat16* ATb  = (__hip_bfloat16*)(ws + off); off += 1048576;
    __hip_bfloat16* patchWt = (__hip_bfloat16*)(ws + off); off += 32768;
    __hip_bfloat16* qkvWt   = (__hip_bfloat16*)(ws + off); off += 98304;
    __hip_bfloat16* WoWt    = (__hip_bfloat16*)(ws + off); off += 32768;
    __hip_bfloat16* W1t     = (__hip_bfloat16*)(ws + off); off += 131072;
    __hip_bfloat16* W2t     = (__hip_bfloat16*)(ws + off); off += 131072;
    __hip_bfloat16* pyrWt   = (__hip_bfloat16*)(ws + off); off += 81920;
    __hip_bfloat16* MIDb = (__hip_bfloat16*)UNION;
    __hip_bfloat16* QKVb = (__hip_bfloat16*)UNION;

    prep_kernel<<<2528, 256, 0, stream>>>(
        patch_W, Wqkv, Wo, ff_W1, ff_W2, pyr_W, x_in,
        patchWt, qkvWt, WoWt, W1t, W2t, pyrWt, POS, Xb);

    patchln_kernel<<<256, 256, 0, stream>>>(Xb, patchWt, patch_b, ln_g, ln_b, POS, H, Hb);

    for (int it = 0; it < 5; it++) {
        bgemm_kernel<1, false, true, false, 128, 128><<<dim3(8, 64), 256, 0, stream>>>(
            Hb, W1t, ff_b1, nullptr, nullptr, MIDb, ROWS_, HIDEF_, D_, nullptr);
        bgemm_kernel<0, false, true, false, 64, 64><<<dim3(4, 128), 256, 0, stream>>>(
            MIDb, W2t, ff_b2, nullptr, nullptr, Tb, ROWS_, D_, HIDEF_, nullptr);
        bgemm_kernel<0, false, true, false, 128, 64><<<dim3(12, 64), 256, 0, stream>>>(
            Tb, qkvWt, bqkv, nullptr, nullptr, QKVb, ROWS_, 768, D_, nullptr);
        attn_kernel<<<dim3(4, HEADS_, B_), 256, 0, stream>>>(QKVb, ATb);
        bgemm_kernel<0, true, false, true, 64, 64><<<dim3(4, 128), 256, 0, stream>>>(
            ATb, WoWt, bo, H, T, nullptr, ROWS_, D_, D_, BNP);
        bn_applyfin_kernel<<<256, 256, 0, stream>>>(T, BNP, 128, bn1_g, bn1_b, H, Hb);
        bgemm_kernel<1, false, true, false, 128, 128><<<dim3(8, 64), 256, 0, stream>>>(
            Hb, W1t, ff_b1, nullptr, nullptr, MIDb, ROWS_, HIDEF_, D_, nullptr);
        bgemm_kernel<0, true, false, true, 64, 64><<<dim3(4, 128), 256, 0, stream>>>(
            MIDb, W2t, ff_b2, H, T, nullptr, ROWS_, D_, HIDEF_, BNP);
        if (it < 4) {
            bnpatch_kernel<true><<<256, 256, 0, stream>>>(
                T, BNP, bn2_g, bn2_b, patchWt, patch_b, ln_g, ln_b, POS,
                pyrWt + (size_t)it * D_ * PYOUT_, pyr_b + it * PYOUT_, it, FLAT, H, Hb);
        } else {
            bnpatch_kernel<false><<<256, 256, 0, stream>>>(
                T, BNP, bn2_g, bn2_b, patchWt, patch_b, ln_g, ln_b, POS,
                pyrWt + (size_t)it * D_ * PYOUT_, pyr_b + it * PYOUT_, it, FLAT, H, Hb);
        }
    }

    fcl_partial_kernel<<<FCL_CHUNKS, 256, 0, stream>>>(FLAT, fcl_W, PART);
    fcl_reduce_kernel<<<64, 256, 0, stream>>>(PART, fcl_b, ADD);
    head_kernel<<<1, 256, 0, stream>>>(ADD, addbn_g, addbn_b,
        cls_W1, cls_b1, cls_W2, cls_b2, box_W1, box_b1, box_W2, box_b2, out);
    (void)in_sizes; (void)n_in; (void)out_size; (void)ws_size;
}